// Round 1
// baseline (2264.415 us; speedup 1.0000x reference)
//
#include <hip/hip_runtime.h>
#include <hip/hip_bf16.h>
#include <math.h>

#define NN 50000
#define NE 400000
#define CD 128
#define NT 6250         // edge tiles of 64
#define NB 512          // persistent edge blocks
#define HBINS 50176     // 196*256, >= NN

typedef __attribute__((ext_vector_type(8))) short bf16x8;
typedef __attribute__((ext_vector_type(4))) float f32x4;

__device__ __forceinline__ float silu_f(float z) {
    return z * __builtin_amdgcn_rcpf(1.f + __expf(-z));
}
__device__ __forceinline__ unsigned short f2bf(float x) {
    unsigned int u = __float_as_uint(x);
    u = (u + 0x7FFFu + ((u >> 16) & 1u)) >> 16;
    return (unsigned short)u;
}
__device__ __forceinline__ float bf2f(unsigned short h) {
    return __uint_as_float(((unsigned int)h) << 16);
}
__device__ __forceinline__ unsigned pk_bf16(float a, float b) {
    union { __hip_bfloat162 h2; unsigned u; } cv;
    cv.h2 = __float22bfloat162_rn(make_float2(a, b));
    return cv.u;
}
__device__ __forceinline__ void gload_lds16(const unsigned short* g, unsigned short* l) {
    __builtin_amdgcn_global_load_lds(
        (const __attribute__((address_space(1))) unsigned int*)g,
        (__attribute__((address_space(3))) unsigned int*)l, 16, 0, 0);
}

// ======================= edge sort by dst (counting sort) ===================
__global__ __launch_bounds__(256) void hist_kernel(
        const int* __restrict__ dst, int* __restrict__ hist)
{
    int e = blockIdx.x * 256 + threadIdx.x;
    if (e < NE) atomicAdd(&hist[dst[e]], 1);
}

__global__ __launch_bounds__(256) void scan1_kernel(
        const int* __restrict__ hist, int* __restrict__ offs, int* __restrict__ bsum)
{
    __shared__ int sh[256];
    const int t = threadIdx.x;
    const int i = blockIdx.x * 256 + t;
    int v = hist[i];
    sh[t] = v;
    __syncthreads();
    for (int off = 1; off < 256; off <<= 1) {
        int x = (t >= off) ? sh[t - off] : 0;
        __syncthreads();
        sh[t] += x;
        __syncthreads();
    }
    offs[i] = sh[t] - v;                 // exclusive
    if (t == 255) bsum[blockIdx.x] = sh[t];
}

__global__ __launch_bounds__(256) void scan2_kernel(int* __restrict__ bsum)
{
    __shared__ int sh[256];
    const int t = threadIdx.x;
    int v = (t < 196) ? bsum[t] : 0;
    sh[t] = v;
    __syncthreads();
    for (int off = 1; off < 256; off <<= 1) {
        int x = (t >= off) ? sh[t - off] : 0;
        __syncthreads();
        sh[t] += x;
        __syncthreads();
    }
    if (t < 196) bsum[t] = sh[t] - v;    // exclusive
}

__global__ __launch_bounds__(256) void scan3_kernel(
        const int* __restrict__ offs, const int* __restrict__ bsum,
        int* __restrict__ cursor)
{
    const int i = blockIdx.x * 256 + threadIdx.x;
    cursor[i] = offs[i] + bsum[blockIdx.x];
}

__global__ __launch_bounds__(256) void scatter_kernel(
        const int* __restrict__ eidx, const float* __restrict__ edist,
        int* __restrict__ cursor,
        int* __restrict__ ssrc, int* __restrict__ sdst, float* __restrict__ sdist)
{
    int e = blockIdx.x * 256 + threadIdx.x;
    if (e < NE) {
        int d = eidx[NE + e];
        int p = atomicAdd(&cursor[d], 1);
        ssrc[p] = eidx[e];
        sdst[p] = d;
        sdist[p] = edist[e];
    }
}

// ======================= weight prep ========================================
__global__ __launch_bounds__(64) void wbig_prep(
        const float* __restrict__ We2, const float* __restrict__ Wn1,
        const float* __restrict__ Wc1, unsigned short* __restrict__ wbig)
{
    const int l = blockIdx.y;
    const int ntile = blockIdx.x / 10;
    const int ks = blockIdx.x % 10;
    const int lane = threadIdx.x;
    const int n = ntile * 16 + (lane & 15);
    const int kbase = ks * 32 + (lane >> 4) * 8;
    const float* Wn1l = Wn1 + (size_t)l * 320 * 256;
    const float* Wc1l = Wc1 + (size_t)l * 320 * 256;
    const float* We2l = We2 + (size_t)l * 64 * 64;
    const float* W1 = (n < 256) ? Wn1l : Wc1l;
    const int nn = n & 255;
    unsigned short* outp = wbig + ((((size_t)l * 32 + ntile) * 10 + ks) * 64 + lane) * 8;
    #pragma unroll
    for (int j = 0; j < 8; ++j) {
        int k = kbase + j;
        float val;
        if (k < 256) {
            val = W1[(size_t)k * 256 + nn];
        } else {
            int i = k - 256;
            float acc = 0.f;
            #pragma unroll 8
            for (int jj = 0; jj < 64; ++jj)
                acc += We2l[i * 64 + jj] * W1[(size_t)(256 + jj) * 256 + nn];
            val = acc;
        }
        outp[j] = f2bf(val);
    }
}

__global__ __launch_bounds__(64) void wn2_prep(
        const float* __restrict__ Wn2, unsigned short* __restrict__ wn2s)
{
    const int l = blockIdx.y;
    const int ntile = blockIdx.x / 8;
    const int ks = blockIdx.x % 8;
    const int lane = threadIdx.x;
    const int n = ntile * 16 + (lane & 15);
    const int kbase = ks * 32 + (lane >> 4) * 8;
    const float* Wn2l = Wn2 + (size_t)l * 256 * 128;
    unsigned short* outp = wn2s + ((((size_t)l * 8 + ntile) * 8 + ks) * 64 + lane) * 8;
    #pragma unroll
    for (int j = 0; j < 8; ++j)
        outp[j] = f2bf(Wn2l[(size_t)(kbase + j) * 128 + n]);
}

__global__ __launch_bounds__(512) void cep_prep(
        const float* __restrict__ be2,
        const float* __restrict__ Wn1, const float* __restrict__ Wc1,
        const float* __restrict__ bn1, const float* __restrict__ bc1,
        float* __restrict__ cep)
{
    const int l = blockIdx.x;
    const int j = threadIdx.x;
    const int jj = j & 255;
    const float* W1 = ((j < 256) ? Wn1 : Wc1) + (size_t)l * 320 * 256;
    const float* be2l = be2 + l * 64;
    float acc = (j < 256) ? bn1[l * 256 + jj] : bc1[l * 256 + jj];
    #pragma unroll 8
    for (int k = 0; k < 64; ++k)
        acc += be2l[k] * W1[(size_t)(256 + k) * 256 + jj];
    cep[l * 512 + j] = acc;
}

__global__ __launch_bounds__(256) void conv_kernel(
        const float* __restrict__ h, unsigned short* __restrict__ hbf)
{
    const int i = (blockIdx.x * 256 + threadIdx.x) * 4;
    float4 v = *(const float4*)(h + i);
    *(uint2*)(hbf + i) = make_uint2(pk_bf16(v.x, v.y), pk_bf16(v.z, v.w));
}

// ======================= persistent pipelined edge kernel ===================
// 512 blocks x 512 threads (8 waves), 1 block/CU (~132 KB LDS).
// Each block owns a contiguous range of 64-edge tiles (dst-sorted).
// Per-tile pipeline: stage(T+1) via async global_load_lds (XOR-swizzled
// source, linear LDS dest) issued at tile-T start; GEMM(T); epilogue;
// MFMA segment-sum (indicator matrix G, t stored transposed) + atomics.
// Node half uses operand-swapped MFMA so t lands col-major (b64 writes).
// All barriers are plain __syncthreads(): issue-to-use distance is a full
// tile, so the implicit vmcnt(0) drain is ~free.
// ---------------------------------------------------------------------------
__global__ __launch_bounds__(512, 2) void edge_kernel(
        const int* __restrict__ ssrc, const int* __restrict__ sdst,
        const float* __restrict__ sdist,
        const float* __restrict__ We1l, const float* __restrict__ be1l,
        const unsigned short* __restrict__ hbf,
        const unsigned short* __restrict__ wbig_l,
        const float* __restrict__ cep_l,
        const float* __restrict__ Wc2l,
        const float* __restrict__ x_in,
        float* __restrict__ Tbar, float* __restrict__ x_out)
{
    __shared__ __align__(16) unsigned short s_h[2][64 * 256]; // swizzled h rows (dbuf)
    __shared__ __align__(16) unsigned short s_e[2][64][72];   // edge-mlp act (dbuf)
    __shared__ __align__(16) unsigned short s_tT[256][72];    // t transposed, col-swizzled
    __shared__ __align__(16) unsigned short s_G[64][72];      // run indicator, col-swizzled
    __shared__ __align__(16) float s_cw[64][4];
    __shared__ int s_sd[2][2][64];                            // [buf][src/dst][row]
    __shared__ int s_rdst[64];
    __shared__ unsigned long long s_mask;

    const int tid = threadIdx.x;
    const int wave = tid >> 6, lane = tid & 63;
    const int m = lane & 15, q = lane >> 4;
    const int lo = (int)(((long long)blockIdx.x * NT) / NB);
    const int hi = (int)(((long long)(blockIdx.x + 1) * NT) / NB);

    auto stage_issue = [&](int T) {
        const int pp = T & 1;
        #pragma unroll
        for (int it = 0; it < 4; ++it) {
            const int slot = it * 512 + wave * 64 + lane;      // linear LDS dest
            const int row = slot >> 5;
            const int c = (slot & 31) ^ (row & 7);             // swizzled source chunk
            const int node = s_sd[pp][c >> 4][row];            // c<16: src, else dst
            gload_lds16(hbf + (size_t)node * CD + (c & 15) * 8,
                        &s_h[pp][slot * 8]);
        }
    };
    auto ea_comp = [&](int T) {
        const int pp = T & 1;
        const int e = tid >> 3, j0 = (tid & 7) * 8;
        const float d = sdist[T * 64 + e];
        unsigned tmp[4];
        #pragma unroll
        for (int j = 0; j < 4; ++j) {
            float a = silu_f(d * We1l[j0 + 2 * j] + be1l[j0 + 2 * j]);
            float b = silu_f(d * We1l[j0 + 2 * j + 1] + be1l[j0 + 2 * j + 1]);
            tmp[j] = pk_bf16(a, b);
        }
        *(bf16x8*)&s_e[pp][e][j0] = *(const bf16x8*)tmp;
    };

    int sv_c = 0, dv_c = 0, sv_n = 0, dv_n = 0;               // wave0: edge src/dst regs
    float xs0 = 0.f, xs1 = 0.f, xs2 = 0.f, xd0 = 0.f, xd1 = 0.f, xd2 = 0.f;

    // ---- prologue: stage first tile ----
    if (wave == 0) {
        sv_c = ssrc[lo * 64 + lane];
        dv_c = sdst[lo * 64 + lane];
        s_sd[lo & 1][0][lane] = sv_c;
        s_sd[lo & 1][1][lane] = dv_c;
    }
    __syncthreads();
    stage_issue(lo);
    ea_comp(lo);
    if (wave == 0 && lo + 1 < hi) {
        sv_n = ssrc[(lo + 1) * 64 + lane];
        dv_n = sdst[(lo + 1) * 64 + lane];
        s_sd[(lo + 1) & 1][0][lane] = sv_n;
        s_sd[(lo + 1) & 1][1][lane] = dv_n;
    }

    for (int T = lo; T < hi; ++T) {
        const int pb = T & 1;

        // zero run-indicator matrix (read two barriers later)
        for (int i = tid; i < 64 * 72 / 2; i += 512)
            ((unsigned*)s_G)[i] = 0u;
        __syncthreads();                                      // b1: stage(T) complete

        if (wave == 0) {
            int nxtd = __shfl(dv_c, lane + 1);
            if (lane == 63) nxtd = -1;
            unsigned long long mk = __ballot(dv_c != nxtd);
            int rid = __popcll(mk & ((1ull << lane) - 1ull));
            s_G[rid][lane ^ ((rid & 3) << 3)] = 0x3F80;       // bf16 1.0, col-swizzled
            if ((mk >> lane) & 1ull) s_rdst[rid] = dv_c;
            if (lane == 0) s_mask = mk;
            xs0 = x_in[sv_c * 3];     xs1 = x_in[sv_c * 3 + 1]; xs2 = x_in[sv_c * 3 + 2];
            xd0 = x_in[dv_c * 3];     xd1 = x_in[dv_c * 3 + 1]; xd2 = x_in[dv_c * 3 + 2];
        }
        if (T + 1 < hi) stage_issue(T + 1);                   // async, lands before b2

        // ---- GEMM(T) ----
        f32x4 acc[4][4];
        #pragma unroll
        for (int nt = 0; nt < 4; ++nt)
            #pragma unroll
            for (int mt = 0; mt < 4; ++mt)
                acc[nt][mt] = (f32x4){0.f, 0.f, 0.f, 0.f};

        if (wave < 4) {
            // node half, swapped operands: C rows = edges, cols = weight-cols
            #pragma unroll
            for (int ks = 0; ks < 10; ++ks) {
                bf16x8 ef[4];
                #pragma unroll
                for (int mt = 0; mt < 4; ++mt) {
                    const int row = mt * 16 + m;
                    ef[mt] = (ks < 8)
                        ? *(const bf16x8*)&s_h[pb][row * 256 + ((ks * 4 + q) ^ (m & 7)) * 8]
                        : *(const bf16x8*)&s_e[pb][row][(ks - 8) * 32 + q * 8];
                }
                #pragma unroll
                for (int nt = 0; nt < 4; ++nt) {
                    bf16x8 wf = *(const bf16x8*)(wbig_l +
                        ((size_t)((wave * 4 + nt) * 10 + ks) * 64 + lane) * 8);
                    #pragma unroll
                    for (int mt = 0; mt < 4; ++mt)
                        acc[nt][mt] = __builtin_amdgcn_mfma_f32_16x16x32_bf16(
                            ef[mt], wf, acc[nt][mt], 0, 0, 0);
                }
            }
        } else {
            // coord half, original orientation: C cols = edges
            #pragma unroll
            for (int ks = 0; ks < 10; ++ks) {
                bf16x8 ef[4];
                #pragma unroll
                for (int mt = 0; mt < 4; ++mt) {
                    const int row = mt * 16 + m;
                    ef[mt] = (ks < 8)
                        ? *(const bf16x8*)&s_h[pb][row * 256 + ((ks * 4 + q) ^ (m & 7)) * 8]
                        : *(const bf16x8*)&s_e[pb][row][(ks - 8) * 32 + q * 8];
                }
                #pragma unroll
                for (int nt = 0; nt < 4; ++nt) {
                    bf16x8 wf = *(const bf16x8*)(wbig_l +
                        ((size_t)((wave * 4 + nt) * 10 + ks) * 64 + lane) * 8);
                    #pragma unroll
                    for (int mt = 0; mt < 4; ++mt)
                        acc[nt][mt] = __builtin_amdgcn_mfma_f32_16x16x32_bf16(
                            wf, ef[mt], acc[nt][mt], 0, 0, 0);
                }
            }
        }
        __syncthreads();                                      // b2: s_h/s_e reads done

        // ---- epilogue ----
        if (wave < 4) {
            // t -> transposed LDS: lane holds 4 consecutive edges per (nt,mt)
            #pragma unroll
            for (int nt = 0; nt < 4; ++nt) {
                const int col = (wave * 4 + nt) * 16 + m;
                const float ce = cep_l[col];
                #pragma unroll
                for (int mt = 0; mt < 4; ++mt) {
                    float t0 = silu_f(acc[nt][mt][0] + ce);
                    float t1 = silu_f(acc[nt][mt][1] + ce);
                    float t2 = silu_f(acc[nt][mt][2] + ce);
                    float t3 = silu_f(acc[nt][mt][3] + ce);
                    *(uint2*)&s_tT[col][(mt * 16 + q * 4) ^ ((m & 3) << 3)] =
                        make_uint2(pk_bf16(t0, t1), pk_bf16(t2, t3));
                }
            }
        } else {
            float pcw[4] = {0.f, 0.f, 0.f, 0.f};
            #pragma unroll
            for (int nt = 0; nt < 4; ++nt) {
                const int c0 = (wave * 4 + nt) * 16 + q * 4;   // 256..511
                const float4 ce = *(const float4*)&cep_l[c0];
                const float4 wv = *(const float4*)&Wc2l[c0 - 256];
                #pragma unroll
                for (int mt = 0; mt < 4; ++mt) {
                    pcw[mt] += silu_f(acc[nt][mt][0] + ce.x) * wv.x;
                    pcw[mt] += silu_f(acc[nt][mt][1] + ce.y) * wv.y;
                    pcw[mt] += silu_f(acc[nt][mt][2] + ce.z) * wv.z;
                    pcw[mt] += silu_f(acc[nt][mt][3] + ce.w) * wv.w;
                }
            }
            #pragma unroll
            for (int mt = 0; mt < 4; ++mt) {
                pcw[mt] += __shfl_xor(pcw[mt], 16);
                pcw[mt] += __shfl_xor(pcw[mt], 32);
            }
            if (lane < 16)
                #pragma unroll
                for (int mt = 0; mt < 4; ++mt)
                    s_cw[mt * 16 + lane][wave - 4] = pcw[mt];
        }
        __syncthreads();                                      // b3: tT/cw/G ready

        // ---- MFMA segment-sum: out^T[c][r] = sum_e tT[c][e]*G[e][r] ----
        {
            const unsigned long long mask = s_mask;
            const int nruns = __popcll(mask);
            f32x4 a2[2][4];
            #pragma unroll
            for (int mt2 = 0; mt2 < 2; ++mt2)
                #pragma unroll
                for (int nt = 0; nt < 4; ++nt)
                    a2[mt2][nt] = (f32x4){0.f, 0.f, 0.f, 0.f};
            #pragma unroll
            for (int ks = 0; ks < 2; ++ks) {
                bf16x8 af[2], bfr[4];
                #pragma unroll
                for (int mt2 = 0; mt2 < 2; ++mt2)
                    af[mt2] = *(const bf16x8*)&s_tT[(wave * 2 + mt2) * 16 + m]
                                               [(ks * 32 + q * 8) ^ ((m & 3) << 3)];
                #pragma unroll
                for (int nt = 0; nt < 4; ++nt)
                    bfr[nt] = *(const bf16x8*)&s_G[nt * 16 + m]
                                               [(ks * 32 + q * 8) ^ ((m & 3) << 3)];
                #pragma unroll
                for (int mt2 = 0; mt2 < 2; ++mt2)
                    #pragma unroll
                    for (int nt = 0; nt < 4; ++nt)
                        a2[mt2][nt] = __builtin_amdgcn_mfma_f32_16x16x32_bf16(
                            af[mt2], bfr[nt], a2[mt2][nt], 0, 0, 0);
            }
            #pragma unroll
            for (int nt = 0; nt < 4; ++nt) {
                const int r = nt * 16 + m;
                if (r < nruns) {
                    float* bp = Tbar + (size_t)s_rdst[r] * 256;
                    #pragma unroll
                    for (int mt2 = 0; mt2 < 2; ++mt2) {
                        const int c = (wave * 2 + mt2) * 16 + q * 4;
                        atomicAdd(&bp[c],     a2[mt2][nt][0]);
                        atomicAdd(&bp[c + 1], a2[mt2][nt][1]);
                        atomicAdd(&bp[c + 2], a2[mt2][nt][2]);
                        atomicAdd(&bp[c + 3], a2[mt2][nt][3]);
                    }
                }
            }
        }
        if (wave == 0) {
            // coord finalize (x frozen during dispatch; xin prefetched at b1)
            const float4 pv = *(const float4*)&s_cw[lane][0];
            const float cw = pv.x + pv.y + pv.z + pv.w;
            atomicAdd(&x_out[dv_c * 3],     cw * (xs0 - xd0));
            atomicAdd(&x_out[dv_c * 3 + 1], cw * (xs1 - xd1));
            atomicAdd(&x_out[dv_c * 3 + 2], cw * (xs2 - xd2));
        }
        if (T + 1 < hi) ea_comp(T + 1);
        if (wave == 0) {
            sv_c = sv_n; dv_c = dv_n;
            if (T + 2 < hi) {
                sv_n = ssrc[(T + 2) * 64 + lane];
                dv_n = sdst[(T + 2) * 64 + lane];
                s_sd[(T + 2) & 1][0][lane] = sv_n;
                s_sd[(T + 2) & 1][1][lane] = dv_n;
            }
        }
        __syncthreads();                                      // b4: protect tT/G/cw/s_sd
    }
}

// ======================= node kernel: h += Tbar@Wn2 + deg*bn2 ===============
__global__ __launch_bounds__(256) void node_kernel(
        const float* __restrict__ Tbar, const int* __restrict__ deg,
        const unsigned short* __restrict__ wn2_l, const float* __restrict__ bn2l,
        float* __restrict__ h, unsigned short* __restrict__ hbf)
{
    const int nb = blockIdx.x * 64;
    const int tid = threadIdx.x;
    const int wave = tid >> 6, lane = tid & 63;
    const int m = lane & 15, q = lane >> 4;

    f32x4 acc[2][4];
    #pragma unroll
    for (int nt = 0; nt < 2; ++nt)
        #pragma unroll
        for (int mt = 0; mt < 4; ++mt)
            acc[nt][mt] = (f32x4){0.f, 0.f, 0.f, 0.f};

    #pragma unroll
    for (int ks = 0; ks < 8; ++ks) {
        bf16x8 af[4];
        #pragma unroll
        for (int mt = 0; mt < 4; ++mt) {
            const int node = nb + mt * 16 + m;
            if (node < NN) {
                const float* tp = Tbar + (size_t)node * 256 + ks * 32 + q * 8;
                float4 f0 = *(const float4*)tp;
                float4 f1 = *(const float4*)(tp + 4);
                unsigned u[4] = { pk_bf16(f0.x, f0.y), pk_bf16(f0.z, f0.w),
                                  pk_bf16(f1.x, f1.y), pk_bf16(f1.z, f1.w) };
                af[mt] = *(const bf16x8*)u;
            } else {
                af[mt] = (bf16x8){0,0,0,0,0,0,0,0};
            }
        }
        #pragma unroll
        for (int nt = 0; nt < 2; ++nt) {
            bf16x8 wf = *(const bf16x8*)(wn2_l +
                ((size_t)((wave * 2 + nt) * 8 + ks) * 64 + lane) * 8);
            #pragma unroll
            for (int mt = 0; mt < 4; ++mt)
                acc[nt][mt] = __builtin_amdgcn_mfma_f32_16x16x32_bf16(af[mt], wf, acc[nt][mt], 0, 0, 0);
        }
    }
    #pragma unroll
    for (int nt = 0; nt < 2; ++nt) {
        const int col = (wave * 2 + nt) * 16 + m;
        const float bb = bn2l[col];
        #pragma unroll
        for (int mt = 0; mt < 4; ++mt) {
            #pragma unroll
            for (int i = 0; i < 4; ++i) {
                const int node = nb + mt * 16 + q * 4 + i;
                if (node < NN) {
                    float val = acc[nt][mt][i] + (float)deg[node] * bb
                              + h[(size_t)node * CD + col];
                    h[(size_t)node * CD + col] = val;
                    hbf[(size_t)node * CD + col] = f2bf(val);
                }
            }
        }
    }
}

// ======================= final layernorm ====================================
__global__ __launch_bounds__(256) void final_kernel(
        const float* __restrict__ h, const float* __restrict__ x,
        const float* __restrict__ gamma, const float* __restrict__ beta,
        float* __restrict__ out)
{
    const int lane = threadIdx.x & 63;
    const int wave = threadIdx.x >> 6;
    const int n = blockIdx.x * 4 + wave;
    float v0 = h[(size_t)n * CD + lane];
    float v1 = h[(size_t)n * CD + 64 + lane];
    float ssum = v0 + v1;
    for (int off = 32; off; off >>= 1) ssum += __shfl_xor(ssum, off);
    float mu = ssum * (1.f / 128.f);
    float d0 = v0 - mu, d1 = v1 - mu;
    float sq = d0 * d0 + d1 * d1;
    for (int off = 32; off; off >>= 1) sq += __shfl_xor(sq, off);
    float rstd = rsqrtf(sq * (1.f / 128.f) + 1e-5f);
    out[(size_t)n * CD + lane]      = gamma[lane]      * d0 * rstd + beta[lane];
    out[(size_t)n * CD + 64 + lane] = gamma[64 + lane] * d1 * rstd + beta[64 + lane];
    if (threadIdx.x < 12) {
        int nn = blockIdx.x * 4 + threadIdx.x / 3;
        int c = threadIdx.x % 3;
        out[(size_t)NN * CD + nn * 3 + c] = x[nn * 3 + c];
    }
}

static inline size_t align_up(size_t v) { return (v + 255) & ~(size_t)255; }

extern "C" void kernel_launch(void* const* d_in, const int* in_sizes, int n_in,
                              void* d_out, int out_size, void* d_ws, size_t ws_size,
                              hipStream_t stream)
{
    const float* single = (const float*)d_in[0];
    const float* coords = (const float*)d_in[2];
    const int*   eidx   = (const int*)d_in[3];
    const float* edist  = (const float*)d_in[4];
    const float* We1 = (const float*)d_in[5];
    const float* be1 = (const float*)d_in[6];
    const float* We2 = (const float*)d_in[7];
    const float* be2 = (const float*)d_in[8];
    const float* Wn1 = (const float*)d_in[9];
    const float* bn1 = (const float*)d_in[10];
    const float* Wn2 = (const float*)d_in[11];
    const float* bn2 = (const float*)d_in[12];
    const float* Wc1 = (const float*)d_in[13];
    const float* bc1 = (const float*)d_in[14];
    const float* Wc2 = (const float*)d_in[15];
    const float* gamma = (const float*)d_in[16];
    const float* beta  = (const float*)d_in[17];
    float* out = (float*)d_out;

    char* w = (char*)d_ws;
    float* h0  = (float*)w;  w += align_up((size_t)NN * CD * 4);
    float* x0  = (float*)w;  w += align_up((size_t)NN * 3 * 4);
    float* x1  = (float*)w;  w += align_up((size_t)NN * 3 * 4);
    unsigned short* hbf  = (unsigned short*)w; w += align_up((size_t)NN * CD * 2);
    unsigned short* wbig = (unsigned short*)w; w += align_up((size_t)4 * 512 * 320 * 2);
    unsigned short* wn2s = (unsigned short*)w; w += align_up((size_t)4 * 256 * 128 * 2);
    float* cep = (float*)w;  w += align_up((size_t)4 * 512 * 4);
    int* hist   = (int*)w;   w += align_up((size_t)HBINS * 4);
    int* offs   = (int*)w;   w += align_up((size_t)HBINS * 4);
    int* cursor = (int*)w;   w += align_up((size_t)HBINS * 4);
    int* bsum   = (int*)w;   w += align_up((size_t)256 * 4);
    int* ssrc   = (int*)w;   w += align_up((size_t)NE * 4);
    int* sdst   = (int*)w;   w += align_up((size_t)NE * 4);
    float* sdist = (float*)w; w += align_up((size_t)NE * 4);
    float* Tbar = (float*)w; w += align_up((size_t)NN * 256 * 4);

    // ---- sort edges by dst (once; constant across layers) ----
    hipMemsetAsync(hist, 0, (size_t)HBINS * 4, stream);
    hist_kernel<<<(NE + 255) / 256, 256, 0, stream>>>(eidx + NE, hist);
    scan1_kernel<<<HBINS / 256, 256, 0, stream>>>(hist, offs, bsum);
    scan2_kernel<<<1, 256, 0, stream>>>(bsum);
    scan3_kernel<<<HBINS / 256, 256, 0, stream>>>(offs, bsum, cursor);
    scatter_kernel<<<(NE + 255) / 256, 256, 0, stream>>>(eidx, edist, cursor, ssrc, sdst, sdist);

    // ---- weight prep ----
    wbig_prep<<<dim3(320, 4), 64, 0, stream>>>(We2, Wn1, Wc1, wbig);
    wn2_prep<<<dim3(64, 4), 64, 0, stream>>>(Wn2, wn2s);
    cep_prep<<<4, 512, 0, stream>>>(be2, Wn1, Wc1, bn1, bc1, cep);

    hipMemcpyAsync(h0, single, (size_t)NN * CD * 4, hipMemcpyDeviceToDevice, stream);
    hipMemcpyAsync(x0, coords, (size_t)NN * 3 * 4, hipMemcpyDeviceToDevice, stream);
    conv_kernel<<<(NN * CD) / 1024, 256, 0, stream>>>(single, hbf);

    float* xc = x0; float* xn = x1;
    for (int l = 0; l < 4; ++l) {
        hipMemsetAsync(Tbar, 0, (size_t)NN * 256 * 4, stream);
        hipMemcpyAsync(xn, xc, (size_t)NN * 3 * 4, hipMemcpyDeviceToDevice, stream);
        edge_kernel<<<NB, 512, 0, stream>>>(
            ssrc, sdst, sdist,
            We1 + l * 64, be1 + l * 64,
            hbf,
            wbig + (size_t)l * 512 * 320,
            cep + l * 512,
            Wc2 + l * 256,
            xc, Tbar, xn);
        node_kernel<<<(NN + 63) / 64, 256, 0, stream>>>(
            Tbar, hist,
            wn2s + (size_t)l * 256 * 128,
            bn2 + l * CD, h0, hbf);
        float* t = xc; xc = xn; xn = t;
    }
    final_kernel<<<NN / 4, 256, 0, stream>>>(h0, xc, gamma, beta, out);
}

// Round 2
// 2075.527 us; speedup vs baseline: 1.0910x; 1.0910x over previous
//
#include <hip/hip_runtime.h>
#include <hip/hip_bf16.h>
#include <math.h>

#define NN 50000
#define NE 400000
#define CD 128
#define EPB 64          // edges per block in edge_kernel
#define HBINS 50176     // 196*256, >= NN

typedef __attribute__((ext_vector_type(8))) short bf16x8;
typedef __attribute__((ext_vector_type(4))) float f32x4;

__device__ __forceinline__ float silu_f(float z) {
    return z * __builtin_amdgcn_rcpf(1.f + __expf(-z));
}
__device__ __forceinline__ unsigned short f2bf(float x) {
    unsigned int u = __float_as_uint(x);
    u = (u + 0x7FFFu + ((u >> 16) & 1u)) >> 16;
    return (unsigned short)u;
}
__device__ __forceinline__ float bf2f(unsigned short h) {
    return __uint_as_float(((unsigned int)h) << 16);
}
__device__ __forceinline__ unsigned pk_bf16(float a, float b) {
    union { __hip_bfloat162 h2; unsigned u; } cv;
    cv.h2 = __float22bfloat162_rn(make_float2(a, b));
    return cv.u;
}

// ======================= edge sort by dst (counting sort) ===================
__global__ __launch_bounds__(256) void hist_kernel(
        const int* __restrict__ dst, int* __restrict__ hist)
{
    int e = blockIdx.x * 256 + threadIdx.x;
    if (e < NE) atomicAdd(&hist[dst[e]], 1);
}

__global__ __launch_bounds__(256) void scan1_kernel(
        const int* __restrict__ hist, int* __restrict__ offs, int* __restrict__ bsum)
{
    __shared__ int sh[256];
    const int t = threadIdx.x;
    const int i = blockIdx.x * 256 + t;
    int v = hist[i];
    sh[t] = v;
    __syncthreads();
    for (int off = 1; off < 256; off <<= 1) {
        int x = (t >= off) ? sh[t - off] : 0;
        __syncthreads();
        sh[t] += x;
        __syncthreads();
    }
    offs[i] = sh[t] - v;                 // exclusive
    if (t == 255) bsum[blockIdx.x] = sh[t];
}

__global__ __launch_bounds__(256) void scan2_kernel(int* __restrict__ bsum)
{
    __shared__ int sh[256];
    const int t = threadIdx.x;
    int v = (t < 196) ? bsum[t] : 0;
    sh[t] = v;
    __syncthreads();
    for (int off = 1; off < 256; off <<= 1) {
        int x = (t >= off) ? sh[t - off] : 0;
        __syncthreads();
        sh[t] += x;
        __syncthreads();
    }
    if (t < 196) bsum[t] = sh[t] - v;    // exclusive
}

__global__ __launch_bounds__(256) void scan3_kernel(
        const int* __restrict__ offs, const int* __restrict__ bsum,
        int* __restrict__ cursor)
{
    const int i = blockIdx.x * 256 + threadIdx.x;
    cursor[i] = offs[i] + bsum[blockIdx.x];
}

__global__ __launch_bounds__(256) void scatter_kernel(
        const int* __restrict__ eidx, const float* __restrict__ edist,
        int* __restrict__ cursor,
        int* __restrict__ ssrc, int* __restrict__ sdst, float* __restrict__ sdist)
{
    int e = blockIdx.x * 256 + threadIdx.x;
    if (e < NE) {
        int d = eidx[NE + e];
        int p = atomicAdd(&cursor[d], 1);
        ssrc[p] = eidx[e];
        sdst[p] = d;
        sdist[p] = edist[e];
    }
}

// ======================= weight prep ========================================
__global__ __launch_bounds__(64) void wbig_prep(
        const float* __restrict__ We2, const float* __restrict__ Wn1,
        const float* __restrict__ Wc1, unsigned short* __restrict__ wbig)
{
    const int l = blockIdx.y;
    const int ntile = blockIdx.x / 10;
    const int ks = blockIdx.x % 10;
    const int lane = threadIdx.x;
    const int n = ntile * 16 + (lane & 15);
    const int kbase = ks * 32 + (lane >> 4) * 8;
    const float* Wn1l = Wn1 + (size_t)l * 320 * 256;
    const float* Wc1l = Wc1 + (size_t)l * 320 * 256;
    const float* We2l = We2 + (size_t)l * 64 * 64;
    const float* W1 = (n < 256) ? Wn1l : Wc1l;
    const int nn = n & 255;
    unsigned short* outp = wbig + ((((size_t)l * 32 + ntile) * 10 + ks) * 64 + lane) * 8;
    #pragma unroll
    for (int j = 0; j < 8; ++j) {
        int k = kbase + j;
        float val;
        if (k < 256) {
            val = W1[(size_t)k * 256 + nn];
        } else {
            int i = k - 256;
            float acc = 0.f;
            #pragma unroll 8
            for (int jj = 0; jj < 64; ++jj)
                acc += We2l[i * 64 + jj] * W1[(size_t)(256 + jj) * 256 + nn];
            val = acc;
        }
        outp[j] = f2bf(val);
    }
}

__global__ __launch_bounds__(64) void wn2_prep(
        const float* __restrict__ Wn2, unsigned short* __restrict__ wn2s)
{
    const int l = blockIdx.y;
    const int ntile = blockIdx.x / 8;
    const int ks = blockIdx.x % 8;
    const int lane = threadIdx.x;
    const int n = ntile * 16 + (lane & 15);
    const int kbase = ks * 32 + (lane >> 4) * 8;
    const float* Wn2l = Wn2 + (size_t)l * 256 * 128;
    unsigned short* outp = wn2s + ((((size_t)l * 8 + ntile) * 8 + ks) * 64 + lane) * 8;
    #pragma unroll
    for (int j = 0; j < 8; ++j)
        outp[j] = f2bf(Wn2l[(size_t)(kbase + j) * 128 + n]);
}

__global__ __launch_bounds__(512) void cep_prep(
        const float* __restrict__ be2,
        const float* __restrict__ Wn1, const float* __restrict__ Wc1,
        const float* __restrict__ bn1, const float* __restrict__ bc1,
        float* __restrict__ cep)
{
    const int l = blockIdx.x;
    const int j = threadIdx.x;
    const int jj = j & 255;
    const float* W1 = ((j < 256) ? Wn1 : Wc1) + (size_t)l * 320 * 256;
    const float* be2l = be2 + l * 64;
    float acc = (j < 256) ? bn1[l * 256 + jj] : bc1[l * 256 + jj];
    #pragma unroll 8
    for (int k = 0; k < 64; ++k)
        acc += be2l[k] * W1[(size_t)(256 + k) * 256 + jj];
    cep[l * 512 + j] = acc;
}

__global__ __launch_bounds__(256) void conv_kernel(
        const float* __restrict__ h, unsigned short* __restrict__ hbf)
{
    const int i = (blockIdx.x * 256 + threadIdx.x) * 4;
    float4 v = *(const float4*)(h + i);
    *(uint2*)(hbf + i) = make_uint2(pk_bf16(v.x, v.y), pk_bf16(v.z, v.w));
}

// ======================= fused edge kernel (sorted edges) ===================
// Round-0 structure (64 edges/block, 512 threads, 2 blocks/CU) with:
//  * node-half GEMM operand-swapped -> C rows = edges: epilogue writes t
//    TRANSPOSED (s_tT[col][edge], b64-packed, XOR-swizzled) (verified R1)
//  * all-8-wave MFMA segment-sum out^T = tT x G; G built IN REGISTERS from
//    per-edge run ids (s_rid) -- no G buffer, no zeroing, no extra barrier
//  * wf register double-buffer across ks steps (hide L2 latency)
// Atomics remain at block end (no trailing barrier).
// LDS ~80.8 KB -> still 2 blocks/CU.
// ---------------------------------------------------------------------------
__global__ __launch_bounds__(512, 4) void edge_kernel(
        const int* __restrict__ ssrc, const int* __restrict__ sdst,
        const float* __restrict__ sdist,
        const float* __restrict__ We1l, const float* __restrict__ be1l,
        const unsigned short* __restrict__ hbf,
        const unsigned short* __restrict__ wbig_l,
        const float* __restrict__ cep_l,
        const float* __restrict__ Wc2l,
        const float* __restrict__ x_in,
        float* __restrict__ Tbar, float* __restrict__ x_out)
{
    __shared__ __align__(16) unsigned short s_A[EPB][328];   // h rows + edge act
    __shared__ __align__(16) unsigned short s_tT[256][72];   // t transposed (+pad)
    __shared__ __align__(16) float s_cw[EPB][4];
    __shared__ __align__(16) unsigned short s_rid[EPB];      // run id per edge
    __shared__ int s_src[EPB], s_dst[EPB];
    __shared__ int s_rdst[EPB];                              // dst node per run
    __shared__ unsigned long long s_mask;

    const int tid = threadIdx.x;
    const int eb = blockIdx.x * EPB;

    if (tid < EPB) {
        int dv = sdst[eb + tid];
        s_src[tid] = ssrc[eb + tid];
        s_dst[tid] = dv;
        int nxt = (tid == EPB - 1) ? -1 : sdst[eb + tid + 1];
        unsigned long long mk = __ballot(dv != nxt);
        int rid = __popcll(mk & ((1ull << tid) - 1ull));
        s_rid[tid] = (unsigned short)rid;
        if (dv != nxt) s_rdst[rid] = dv;
        if (tid == 0) s_mask = mk;
    }
    {   // s = silu(d*We1+be1) -> s_A[e][256..319]; 8 threads/edge, 8 cols each
        const int e = tid >> 3;
        const int j0 = (tid & 7) * 8;
        const float d = sdist[eb + e];
        unsigned tmp[4];
        #pragma unroll
        for (int j = 0; j < 4; ++j) {
            float a = silu_f(d * We1l[j0 + 2 * j] + be1l[j0 + 2 * j]);
            float b = silu_f(d * We1l[j0 + 2 * j + 1] + be1l[j0 + 2 * j + 1]);
            tmp[j] = pk_bf16(a, b);
        }
        *(bf16x8*)&s_A[e][j0 + 256] = *(const bf16x8*)tmp;
    }
    __syncthreads();   // s_src/s_dst ready for staging

    // ---- stage h rows: 2048 chunks of 16B, 4 per thread ----
    #pragma unroll
    for (int it = 0; it < 4; ++it) {
        const int c = tid + it * 512;
        const int row = c >> 5, ch = c & 31;
        const int node = (ch < 16) ? s_src[row] : s_dst[row];
        const int koff = (ch & 15) * 8;
        bf16x8 v = *(const bf16x8*)(hbf + (size_t)node * CD + koff);
        *(bf16x8*)&s_A[row][ch * 8] = v;
    }
    __syncthreads();

    const int wave = tid >> 6, lane = tid & 63;
    const int m = lane & 15, q = lane >> 4;

    // ---- GEMM1 (wf register double-buffered across ks) ----
    f32x4 acc[4][4];   // [nt][mt]
    #pragma unroll
    for (int nt = 0; nt < 4; ++nt)
        #pragma unroll
        for (int mt = 0; mt < 4; ++mt)
            acc[nt][mt] = (f32x4){0.f, 0.f, 0.f, 0.f};

    bf16x8 wcur[4], wnxt[4];
    #pragma unroll
    for (int nt = 0; nt < 4; ++nt)
        wcur[nt] = *(const bf16x8*)(wbig_l +
            ((size_t)((wave * 4 + nt) * 10 + 0) * 64 + lane) * 8);

    if (wave < 4) {
        // node half, swapped operands: C rows = edges, cols = weight-cols
        #pragma unroll
        for (int ks = 0; ks < 10; ++ks) {
            if (ks < 9)
                #pragma unroll
                for (int nt = 0; nt < 4; ++nt)
                    wnxt[nt] = *(const bf16x8*)(wbig_l +
                        ((size_t)((wave * 4 + nt) * 10 + ks + 1) * 64 + lane) * 8);
            const int koff = ks * 32 + q * 8;
            bf16x8 ef[4];
            #pragma unroll
            for (int mt = 0; mt < 4; ++mt)
                ef[mt] = *(const bf16x8*)&s_A[mt * 16 + m][koff];
            #pragma unroll
            for (int nt = 0; nt < 4; ++nt)
                #pragma unroll
                for (int mt = 0; mt < 4; ++mt)
                    acc[nt][mt] = __builtin_amdgcn_mfma_f32_16x16x32_bf16(
                        ef[mt], wcur[nt], acc[nt][mt], 0, 0, 0);
            if (ks < 9)
                #pragma unroll
                for (int nt = 0; nt < 4; ++nt)
                    wcur[nt] = wnxt[nt];
        }
    } else {
        // coord half, original orientation: C cols = edges
        #pragma unroll
        for (int ks = 0; ks < 10; ++ks) {
            if (ks < 9)
                #pragma unroll
                for (int nt = 0; nt < 4; ++nt)
                    wnxt[nt] = *(const bf16x8*)(wbig_l +
                        ((size_t)((wave * 4 + nt) * 10 + ks + 1) * 64 + lane) * 8);
            const int koff = ks * 32 + q * 8;
            bf16x8 ef[4];
            #pragma unroll
            for (int mt = 0; mt < 4; ++mt)
                ef[mt] = *(const bf16x8*)&s_A[mt * 16 + m][koff];
            #pragma unroll
            for (int nt = 0; nt < 4; ++nt)
                #pragma unroll
                for (int mt = 0; mt < 4; ++mt)
                    acc[nt][mt] = __builtin_amdgcn_mfma_f32_16x16x32_bf16(
                        wcur[nt], ef[mt], acc[nt][mt], 0, 0, 0);
            if (ks < 9)
                #pragma unroll
                for (int nt = 0; nt < 4; ++nt)
                    wcur[nt] = wnxt[nt];
        }
    }

    // ---- epilogue ----
    if (wave < 4) {
        // t -> transposed LDS: lane holds 4 consecutive edges per (nt,mt)
        #pragma unroll
        for (int nt = 0; nt < 4; ++nt) {
            const int col = (wave * 4 + nt) * 16 + m;
            const float ce = cep_l[col];
            #pragma unroll
            for (int mt = 0; mt < 4; ++mt) {
                float t0 = silu_f(acc[nt][mt][0] + ce);
                float t1 = silu_f(acc[nt][mt][1] + ce);
                float t2 = silu_f(acc[nt][mt][2] + ce);
                float t3 = silu_f(acc[nt][mt][3] + ce);
                *(uint2*)&s_tT[col][(mt * 16 + q * 4) ^ ((m & 3) << 3)] =
                    make_uint2(pk_bf16(t0, t1), pk_bf16(t2, t3));
            }
        }
    } else {
        // coord half: in-register partial dot silu(pre)*Wc2
        float p[4] = {0.f, 0.f, 0.f, 0.f};
        #pragma unroll
        for (int nt = 0; nt < 4; ++nt) {
            const int c0 = (wave * 4 + nt) * 16 + q * 4;   // 256..511
            const float4 ce = *(const float4*)&cep_l[c0];
            const float4 wv = *(const float4*)&Wc2l[c0 - 256];
            #pragma unroll
            for (int mt = 0; mt < 4; ++mt) {
                p[mt] += silu_f(acc[nt][mt][0] + ce.x) * wv.x;
                p[mt] += silu_f(acc[nt][mt][1] + ce.y) * wv.y;
                p[mt] += silu_f(acc[nt][mt][2] + ce.z) * wv.z;
                p[mt] += silu_f(acc[nt][mt][3] + ce.w) * wv.w;
            }
        }
        #pragma unroll
        for (int mt = 0; mt < 4; ++mt) {
            p[mt] += __shfl_xor(p[mt], 16);
            p[mt] += __shfl_xor(p[mt], 32);
        }
        if (lane < 16) {
            #pragma unroll
            for (int mt = 0; mt < 4; ++mt)
                s_cw[mt * 16 + lane][wave - 4] = p[mt];
        }
    }
    __syncthreads();   // s_tT / s_cw ready

    // ---- MFMA segment-sum on all 8 waves: out^T[c][r] = sum_e tT[c][e]G[e][r]
    {
        const unsigned long long mask = s_mask;
        const int nruns = __popcll(mask);
        f32x4 a2[2][4];   // [mt2 = col tile][nt = run tile]
        #pragma unroll
        for (int mt2 = 0; mt2 < 2; ++mt2)
            #pragma unroll
            for (int nt = 0; nt < 4; ++nt)
                a2[mt2][nt] = (f32x4){0.f, 0.f, 0.f, 0.f};
        #pragma unroll
        for (int ks = 0; ks < 2; ++ks) {
            bf16x8 af[2];
            #pragma unroll
            for (int mt2 = 0; mt2 < 2; ++mt2)
                af[mt2] = *(const bf16x8*)&s_tT[(wave * 2 + mt2) * 16 + m]
                                           [(ks * 32 + q * 8) ^ ((m & 3) << 3)];
            const unsigned* rp = (const unsigned*)&s_rid[ks * 32 + q * 8];
            const unsigned r01 = rp[0], r23 = rp[1], r45 = rp[2], r67 = rp[3];
            #pragma unroll
            for (int nt = 0; nt < 4; ++nt) {
                const unsigned n = (unsigned)(nt * 16 + m);
                unsigned gw[4];
                gw[0] = ((r01 & 0xFFFFu) == n ? 0x3F80u : 0u) |
                        ((r01 >> 16)      == n ? 0x3F800000u : 0u);
                gw[1] = ((r23 & 0xFFFFu) == n ? 0x3F80u : 0u) |
                        ((r23 >> 16)      == n ? 0x3F800000u : 0u);
                gw[2] = ((r45 & 0xFFFFu) == n ? 0x3F80u : 0u) |
                        ((r45 >> 16)      == n ? 0x3F800000u : 0u);
                gw[3] = ((r67 & 0xFFFFu) == n ? 0x3F80u : 0u) |
                        ((r67 >> 16)      == n ? 0x3F800000u : 0u);
                const bf16x8 bfr = *(const bf16x8*)gw;
                #pragma unroll
                for (int mt2 = 0; mt2 < 2; ++mt2)
                    a2[mt2][nt] = __builtin_amdgcn_mfma_f32_16x16x32_bf16(
                        af[mt2], bfr, a2[mt2][nt], 0, 0, 0);
            }
        }
        #pragma unroll
        for (int nt = 0; nt < 4; ++nt) {
            const int r = nt * 16 + m;
            if (r < nruns) {
                float* bp = Tbar + (size_t)s_rdst[r] * 256;
                #pragma unroll
                for (int mt2 = 0; mt2 < 2; ++mt2) {
                    const int c = (wave * 2 + mt2) * 16 + q * 4;
                    atomicAdd(&bp[c],     a2[mt2][nt][0]);
                    atomicAdd(&bp[c + 1], a2[mt2][nt][1]);
                    atomicAdd(&bp[c + 2], a2[mt2][nt][2]);
                    atomicAdd(&bp[c + 3], a2[mt2][nt][3]);
                }
            }
        }
    }
    if (wave == 2) {
        // finalize coord weights, scatter x
        const int e = lane;
        float4 pv = *(const float4*)&s_cw[e][0];
        float cw = pv.x + pv.y + pv.z + pv.w;
        int sn = s_src[e], dn = s_dst[e];
        float dx0 = x_in[sn * 3 + 0] - x_in[dn * 3 + 0];
        float dx1 = x_in[sn * 3 + 1] - x_in[dn * 3 + 1];
        float dx2 = x_in[sn * 3 + 2] - x_in[dn * 3 + 2];
        atomicAdd(&x_out[dn * 3 + 0], cw * dx0);
        atomicAdd(&x_out[dn * 3 + 1], cw * dx1);
        atomicAdd(&x_out[dn * 3 + 2], cw * dx2);
    }
}

// ======================= node kernel: h += Tbar@Wn2 + deg*bn2 ===============
__global__ __launch_bounds__(256) void node_kernel(
        const float* __restrict__ Tbar, const int* __restrict__ deg,
        const unsigned short* __restrict__ wn2_l, const float* __restrict__ bn2l,
        float* __restrict__ h, unsigned short* __restrict__ hbf)
{
    const int nb = blockIdx.x * 64;
    const int tid = threadIdx.x;
    const int wave = tid >> 6, lane = tid & 63;
    const int m = lane & 15, q = lane >> 4;

    f32x4 acc[2][4];
    #pragma unroll
    for (int nt = 0; nt < 2; ++nt)
        #pragma unroll
        for (int mt = 0; mt < 4; ++mt)
            acc[nt][mt] = (f32x4){0.f, 0.f, 0.f, 0.f};

    #pragma unroll
    for (int ks = 0; ks < 8; ++ks) {
        bf16x8 af[4];
        #pragma unroll
        for (int mt = 0; mt < 4; ++mt) {
            const int node = nb + mt * 16 + m;
            if (node < NN) {
                const float* tp = Tbar + (size_t)node * 256 + ks * 32 + q * 8;
                float4 f0 = *(const float4*)tp;
                float4 f1 = *(const float4*)(tp + 4);
                unsigned u[4] = { pk_bf16(f0.x, f0.y), pk_bf16(f0.z, f0.w),
                                  pk_bf16(f1.x, f1.y), pk_bf16(f1.z, f1.w) };
                af[mt] = *(const bf16x8*)u;
            } else {
                af[mt] = (bf16x8){0,0,0,0,0,0,0,0};
            }
        }
        #pragma unroll
        for (int nt = 0; nt < 2; ++nt) {
            bf16x8 wf = *(const bf16x8*)(wn2_l +
                ((size_t)((wave * 2 + nt) * 8 + ks) * 64 + lane) * 8);
            #pragma unroll
            for (int mt = 0; mt < 4; ++mt)
                acc[nt][mt] = __builtin_amdgcn_mfma_f32_16x16x32_bf16(af[mt], wf, acc[nt][mt], 0, 0, 0);
        }
    }
    #pragma unroll
    for (int nt = 0; nt < 2; ++nt) {
        const int col = (wave * 2 + nt) * 16 + m;
        const float bb = bn2l[col];
        #pragma unroll
        for (int mt = 0; mt < 4; ++mt) {
            #pragma unroll
            for (int i = 0; i < 4; ++i) {
                const int node = nb + mt * 16 + q * 4 + i;
                if (node < NN) {
                    float val = acc[nt][mt][i] + (float)deg[node] * bb
                              + h[(size_t)node * CD + col];
                    h[(size_t)node * CD + col] = val;
                    hbf[(size_t)node * CD + col] = f2bf(val);
                }
            }
        }
    }
}

// ======================= final layernorm ====================================
__global__ __launch_bounds__(256) void final_kernel(
        const float* __restrict__ h, const float* __restrict__ x,
        const float* __restrict__ gamma, const float* __restrict__ beta,
        float* __restrict__ out)
{
    const int lane = threadIdx.x & 63;
    const int wave = threadIdx.x >> 6;
    const int n = blockIdx.x * 4 + wave;
    float v0 = h[(size_t)n * CD + lane];
    float v1 = h[(size_t)n * CD + 64 + lane];
    float ssum = v0 + v1;
    for (int off = 32; off; off >>= 1) ssum += __shfl_xor(ssum, off);
    float mu = ssum * (1.f / 128.f);
    float d0 = v0 - mu, d1 = v1 - mu;
    float sq = d0 * d0 + d1 * d1;
    for (int off = 32; off; off >>= 1) sq += __shfl_xor(sq, off);
    float rstd = rsqrtf(sq * (1.f / 128.f) + 1e-5f);
    out[(size_t)n * CD + lane]      = gamma[lane]      * d0 * rstd + beta[lane];
    out[(size_t)n * CD + 64 + lane] = gamma[64 + lane] * d1 * rstd + beta[64 + lane];
    if (threadIdx.x < 12) {
        int nn = blockIdx.x * 4 + threadIdx.x / 3;
        int c = threadIdx.x % 3;
        out[(size_t)NN * CD + nn * 3 + c] = x[nn * 3 + c];
    }
}

static inline size_t align_up(size_t v) { return (v + 255) & ~(size_t)255; }

extern "C" void kernel_launch(void* const* d_in, const int* in_sizes, int n_in,
                              void* d_out, int out_size, void* d_ws, size_t ws_size,
                              hipStream_t stream)
{
    const float* single = (const float*)d_in[0];
    const float* coords = (const float*)d_in[2];
    const int*   eidx   = (const int*)d_in[3];
    const float* edist  = (const float*)d_in[4];
    const float* We1 = (const float*)d_in[5];
    const float* be1 = (const float*)d_in[6];
    const float* We2 = (const float*)d_in[7];
    const float* be2 = (const float*)d_in[8];
    const float* Wn1 = (const float*)d_in[9];
    const float* bn1 = (const float*)d_in[10];
    const float* Wn2 = (const float*)d_in[11];
    const float* bn2 = (const float*)d_in[12];
    const float* Wc1 = (const float*)d_in[13];
    const float* bc1 = (const float*)d_in[14];
    const float* Wc2 = (const float*)d_in[15];
    const float* gamma = (const float*)d_in[16];
    const float* beta  = (const float*)d_in[17];
    float* out = (float*)d_out;

    char* w = (char*)d_ws;
    float* h0  = (float*)w;  w += align_up((size_t)NN * CD * 4);
    float* x0  = (float*)w;  w += align_up((size_t)NN * 3 * 4);
    float* x1  = (float*)w;  w += align_up((size_t)NN * 3 * 4);
    unsigned short* hbf  = (unsigned short*)w; w += align_up((size_t)NN * CD * 2);
    unsigned short* wbig = (unsigned short*)w; w += align_up((size_t)4 * 512 * 320 * 2);
    unsigned short* wn2s = (unsigned short*)w; w += align_up((size_t)4 * 256 * 128 * 2);
    float* cep = (float*)w;  w += align_up((size_t)4 * 512 * 4);
    int* hist   = (int*)w;   w += align_up((size_t)HBINS * 4);
    int* offs   = (int*)w;   w += align_up((size_t)HBINS * 4);
    int* cursor = (int*)w;   w += align_up((size_t)HBINS * 4);
    int* bsum   = (int*)w;   w += align_up((size_t)256 * 4);
    int* ssrc   = (int*)w;   w += align_up((size_t)NE * 4);
    int* sdst   = (int*)w;   w += align_up((size_t)NE * 4);
    float* sdist = (float*)w; w += align_up((size_t)NE * 4);
    float* Tbar = (float*)w; w += align_up((size_t)NN * 256 * 4);

    // ---- sort edges by dst (once; constant across layers) ----
    hipMemsetAsync(hist, 0, (size_t)HBINS * 4, stream);
    hist_kernel<<<(NE + 255) / 256, 256, 0, stream>>>(eidx + NE, hist);
    scan1_kernel<<<HBINS / 256, 256, 0, stream>>>(hist, offs, bsum);
    scan2_kernel<<<1, 256, 0, stream>>>(bsum);
    scan3_kernel<<<HBINS / 256, 256, 0, stream>>>(offs, bsum, cursor);
    scatter_kernel<<<(NE + 255) / 256, 256, 0, stream>>>(eidx, edist, cursor, ssrc, sdst, sdist);

    // ---- weight prep ----
    wbig_prep<<<dim3(320, 4), 64, 0, stream>>>(We2, Wn1, Wc1, wbig);
    wn2_prep<<<dim3(64, 4), 64, 0, stream>>>(Wn2, wn2s);
    cep_prep<<<4, 512, 0, stream>>>(be2, Wn1, Wc1, bn1, bc1, cep);

    hipMemcpyAsync(h0, single, (size_t)NN * CD * 4, hipMemcpyDeviceToDevice, stream);
    hipMemcpyAsync(x0, coords, (size_t)NN * 3 * 4, hipMemcpyDeviceToDevice, stream);
    conv_kernel<<<(NN * CD) / 1024, 256, 0, stream>>>(single, hbf);

    float* xc = x0; float* xn = x1;
    for (int l = 0; l < 4; ++l) {
        hipMemsetAsync(Tbar, 0, (size_t)NN * 256 * 4, stream);
        hipMemcpyAsync(xn, xc, (size_t)NN * 3 * 4, hipMemcpyDeviceToDevice, stream);
        edge_kernel<<<NE / EPB, 512, 0, stream>>>(
            ssrc, sdst, sdist,
            We1 + l * 64, be1 + l * 64,
            hbf,
            wbig + (size_t)l * 512 * 320,
            cep + l * 512,
            Wc2 + l * 256,
            xc, Tbar, xn);
        node_kernel<<<(NN + 63) / 64, 256, 0, stream>>>(
            Tbar, hist,
            wn2s + (size_t)l * 256 * 128,
            bn2 + l * CD, h0, hbf);
        float* t = xc; xc = xn; xn = t;
    }
    final_kernel<<<NN / 4, 256, 0, stream>>>(h0, xc, gamma, beta, out);
}

// Round 3
// 1362.199 us; speedup vs baseline: 1.6623x; 1.5237x over previous
//
#include <hip/hip_runtime.h>
#include <hip/hip_bf16.h>
#include <math.h>

#define NN 50000
#define NE 400000
#define CD 128
#define EPB 64          // edges per block in edge_kernel
#define HBINS 50176     // 196*256, >= NN

typedef __attribute__((ext_vector_type(8))) short bf16x8;
typedef __attribute__((ext_vector_type(4))) float f32x4;

__device__ __forceinline__ float silu_f(float z) {
    return z * __builtin_amdgcn_rcpf(1.f + __expf(-z));
}
__device__ __forceinline__ unsigned short f2bf(float x) {
    unsigned int u = __float_as_uint(x);
    u = (u + 0x7FFFu + ((u >> 16) & 1u)) >> 16;
    return (unsigned short)u;
}
__device__ __forceinline__ float bf2f(unsigned short h) {
    return __uint_as_float(((unsigned int)h) << 16);
}
__device__ __forceinline__ unsigned pk_bf16(float a, float b) {
    union { __hip_bfloat162 h2; unsigned u; } cv;
    cv.h2 = __float22bfloat162_rn(make_float2(a, b));
    return cv.u;
}

// ======================= edge sort by dst (counting sort) ===================
__global__ __launch_bounds__(256) void hist_kernel(
        const int* __restrict__ dst, int* __restrict__ hist)
{
    int e = blockIdx.x * 256 + threadIdx.x;
    if (e < NE) atomicAdd(&hist[dst[e]], 1);
}

__global__ __launch_bounds__(256) void scan1_kernel(
        const int* __restrict__ hist, int* __restrict__ offs, int* __restrict__ bsum)
{
    __shared__ int sh[256];
    const int t = threadIdx.x;
    const int i = blockIdx.x * 256 + t;
    int v = hist[i];
    sh[t] = v;
    __syncthreads();
    for (int off = 1; off < 256; off <<= 1) {
        int x = (t >= off) ? sh[t - off] : 0;
        __syncthreads();
        sh[t] += x;
        __syncthreads();
    }
    offs[i] = sh[t] - v;                 // exclusive
    if (t == 255) bsum[blockIdx.x] = sh[t];
}

__global__ __launch_bounds__(256) void scan2_kernel(int* __restrict__ bsum)
{
    __shared__ int sh[256];
    const int t = threadIdx.x;
    int v = (t < 196) ? bsum[t] : 0;
    sh[t] = v;
    __syncthreads();
    for (int off = 1; off < 256; off <<= 1) {
        int x = (t >= off) ? sh[t - off] : 0;
        __syncthreads();
        sh[t] += x;
        __syncthreads();
    }
    if (t < 196) bsum[t] = sh[t] - v;    // exclusive
}

__global__ __launch_bounds__(256) void scan3_kernel(
        const int* __restrict__ offs, const int* __restrict__ bsum,
        int* __restrict__ cursor)
{
    const int i = blockIdx.x * 256 + threadIdx.x;
    cursor[i] = offs[i] + bsum[blockIdx.x];
}

__global__ __launch_bounds__(256) void scatter_kernel(
        const int* __restrict__ eidx, const float* __restrict__ edist,
        int* __restrict__ cursor,
        int* __restrict__ ssrc, int* __restrict__ sdst, float* __restrict__ sdist)
{
    int e = blockIdx.x * 256 + threadIdx.x;
    if (e < NE) {
        int d = eidx[NE + e];
        int p = atomicAdd(&cursor[d], 1);
        ssrc[p] = eidx[e];
        sdst[p] = d;
        sdist[p] = edist[e];
    }
}

// ======================= weight prep ========================================
__global__ __launch_bounds__(64) void wbig_prep(
        const float* __restrict__ We2, const float* __restrict__ Wn1,
        const float* __restrict__ Wc1, unsigned short* __restrict__ wbig)
{
    const int l = blockIdx.y;
    const int ntile = blockIdx.x / 10;
    const int ks = blockIdx.x % 10;
    const int lane = threadIdx.x;
    const int n = ntile * 16 + (lane & 15);
    const int kbase = ks * 32 + (lane >> 4) * 8;
    const float* Wn1l = Wn1 + (size_t)l * 320 * 256;
    const float* Wc1l = Wc1 + (size_t)l * 320 * 256;
    const float* We2l = We2 + (size_t)l * 64 * 64;
    const float* W1 = (n < 256) ? Wn1l : Wc1l;
    const int nn = n & 255;
    unsigned short* outp = wbig + ((((size_t)l * 32 + ntile) * 10 + ks) * 64 + lane) * 8;
    #pragma unroll
    for (int j = 0; j < 8; ++j) {
        int k = kbase + j;
        float val;
        if (k < 256) {
            val = W1[(size_t)k * 256 + nn];
        } else {
            int i = k - 256;
            float acc = 0.f;
            #pragma unroll 8
            for (int jj = 0; jj < 64; ++jj)
                acc += We2l[i * 64 + jj] * W1[(size_t)(256 + jj) * 256 + nn];
            val = acc;
        }
        outp[j] = f2bf(val);
    }
}

__global__ __launch_bounds__(64) void wn2_prep(
        const float* __restrict__ Wn2, unsigned short* __restrict__ wn2s)
{
    const int l = blockIdx.y;
    const int ntile = blockIdx.x / 8;
    const int ks = blockIdx.x % 8;
    const int lane = threadIdx.x;
    const int n = ntile * 16 + (lane & 15);
    const int kbase = ks * 32 + (lane >> 4) * 8;
    const float* Wn2l = Wn2 + (size_t)l * 256 * 128;
    unsigned short* outp = wn2s + ((((size_t)l * 8 + ntile) * 8 + ks) * 64 + lane) * 8;
    #pragma unroll
    for (int j = 0; j < 8; ++j)
        outp[j] = f2bf(Wn2l[(size_t)(kbase + j) * 128 + n]);
}

__global__ __launch_bounds__(512) void cep_prep(
        const float* __restrict__ be2,
        const float* __restrict__ Wn1, const float* __restrict__ Wc1,
        const float* __restrict__ bn1, const float* __restrict__ bc1,
        float* __restrict__ cep)
{
    const int l = blockIdx.x;
    const int j = threadIdx.x;
    const int jj = j & 255;
    const float* W1 = ((j < 256) ? Wn1 : Wc1) + (size_t)l * 320 * 256;
    const float* be2l = be2 + l * 64;
    float acc = (j < 256) ? bn1[l * 256 + jj] : bc1[l * 256 + jj];
    #pragma unroll 8
    for (int k = 0; k < 64; ++k)
        acc += be2l[k] * W1[(size_t)(256 + k) * 256 + jj];
    cep[l * 512 + j] = acc;
}

__global__ __launch_bounds__(256) void conv_kernel(
        const float* __restrict__ h, unsigned short* __restrict__ hbf)
{
    const int i = (blockIdx.x * 256 + threadIdx.x) * 4;
    float4 v = *(const float4*)(h + i);
    *(uint2*)(hbf + i) = make_uint2(pk_bf16(v.x, v.y), pk_bf16(v.z, v.w));
}

// ======================= fused edge kernel (sorted edges) ===================
// Round-0 register-exact GEMM loop (64 VGPR + 64 AGPR acc = full 128 budget;
// NO extra live state -- R2 showed +anything => scratch spill).
//  * node-half GEMM operand-swapped -> epilogue writes t TRANSPOSED
//    (s_tT[col][edge], b64-packed, XOR-swizzled)              [verified R1/R2]
//  * all-8-wave MFMA segment-sum out^T = tT x G, G built in registers
//    from per-edge run ids                                    [verified R2]
//  * NEW: interior runs (dst row owned exclusively by this block, since
//    edges are globally dst-sorted) use plain float4 stores -- only the
//    first/last run of a block can be shared => atomicAdd only there.
// LDS ~80.8 KB -> 2 blocks/CU.
// ---------------------------------------------------------------------------
__global__ __launch_bounds__(512, 4) void edge_kernel(
        const int* __restrict__ ssrc, const int* __restrict__ sdst,
        const float* __restrict__ sdist,
        const float* __restrict__ We1l, const float* __restrict__ be1l,
        const unsigned short* __restrict__ hbf,
        const unsigned short* __restrict__ wbig_l,
        const float* __restrict__ cep_l,
        const float* __restrict__ Wc2l,
        const float* __restrict__ x_in,
        float* __restrict__ Tbar, float* __restrict__ x_out)
{
    __shared__ __align__(16) unsigned short s_A[EPB][328];   // h rows + edge act
    __shared__ __align__(16) unsigned short s_tT[256][72];   // t transposed (+pad)
    __shared__ __align__(16) float s_cw[EPB][4];
    __shared__ __align__(16) unsigned short s_rid[EPB];      // run id per edge
    __shared__ int s_src[EPB], s_dst[EPB];
    __shared__ int s_rdst[EPB];                              // dst node per run
    __shared__ unsigned long long s_mask;

    const int tid = threadIdx.x;
    const int eb = blockIdx.x * EPB;

    if (tid < EPB) {
        int dv = sdst[eb + tid];
        s_src[tid] = ssrc[eb + tid];
        s_dst[tid] = dv;
        int nxt = (tid == EPB - 1) ? -1 : sdst[eb + tid + 1];
        unsigned long long mk = __ballot(dv != nxt);
        int rid = __popcll(mk & ((1ull << tid) - 1ull));
        s_rid[tid] = (unsigned short)rid;
        if (dv != nxt) s_rdst[rid] = dv;
        if (tid == 0) s_mask = mk;
    }
    {   // s = silu(d*We1+be1) -> s_A[e][256..319]; 8 threads/edge, 8 cols each
        const int e = tid >> 3;
        const int j0 = (tid & 7) * 8;
        const float d = sdist[eb + e];
        unsigned tmp[4];
        #pragma unroll
        for (int j = 0; j < 4; ++j) {
            float a = silu_f(d * We1l[j0 + 2 * j] + be1l[j0 + 2 * j]);
            float b = silu_f(d * We1l[j0 + 2 * j + 1] + be1l[j0 + 2 * j + 1]);
            tmp[j] = pk_bf16(a, b);
        }
        *(bf16x8*)&s_A[e][j0 + 256] = *(const bf16x8*)tmp;
    }
    __syncthreads();   // s_src/s_dst ready for staging

    // ---- stage h rows: 2048 chunks of 16B, 4 per thread ----
    #pragma unroll
    for (int it = 0; it < 4; ++it) {
        const int c = tid + it * 512;
        const int row = c >> 5, ch = c & 31;
        const int node = (ch < 16) ? s_src[row] : s_dst[row];
        const int koff = (ch & 15) * 8;
        bf16x8 v = *(const bf16x8*)(hbf + (size_t)node * CD + koff);
        *(bf16x8*)&s_A[row][ch * 8] = v;
    }
    __syncthreads();

    const int wave = tid >> 6, lane = tid & 63;
    const int m = lane & 15, q = lane >> 4;

    // ---- GEMM1 ----
    f32x4 acc[4][4];   // [nt][mt]
    #pragma unroll
    for (int nt = 0; nt < 4; ++nt)
        #pragma unroll
        for (int mt = 0; mt < 4; ++mt)
            acc[nt][mt] = (f32x4){0.f, 0.f, 0.f, 0.f};

    if (wave < 4) {
        // node half, swapped operands: C rows = edges, cols = weight-cols
        #pragma unroll
        for (int ks = 0; ks < 10; ++ks) {
            const int koff = ks * 32 + q * 8;
            bf16x8 ef[4];
            #pragma unroll
            for (int mt = 0; mt < 4; ++mt)
                ef[mt] = *(const bf16x8*)&s_A[mt * 16 + m][koff];
            #pragma unroll
            for (int nt = 0; nt < 4; ++nt) {
                bf16x8 wf = *(const bf16x8*)(wbig_l +
                    ((size_t)((wave * 4 + nt) * 10 + ks) * 64 + lane) * 8);
                #pragma unroll
                for (int mt = 0; mt < 4; ++mt)
                    acc[nt][mt] = __builtin_amdgcn_mfma_f32_16x16x32_bf16(
                        ef[mt], wf, acc[nt][mt], 0, 0, 0);
            }
        }
    } else {
        // coord half, original orientation: C cols = edges
        #pragma unroll
        for (int ks = 0; ks < 10; ++ks) {
            const int koff = ks * 32 + q * 8;
            bf16x8 ef[4];
            #pragma unroll
            for (int mt = 0; mt < 4; ++mt)
                ef[mt] = *(const bf16x8*)&s_A[mt * 16 + m][koff];
            #pragma unroll
            for (int nt = 0; nt < 4; ++nt) {
                bf16x8 wf = *(const bf16x8*)(wbig_l +
                    ((size_t)((wave * 4 + nt) * 10 + ks) * 64 + lane) * 8);
                #pragma unroll
                for (int mt = 0; mt < 4; ++mt)
                    acc[nt][mt] = __builtin_amdgcn_mfma_f32_16x16x32_bf16(
                        wf, ef[mt], acc[nt][mt], 0, 0, 0);
            }
        }
    }

    // ---- epilogue ----
    if (wave < 4) {
        // t -> transposed LDS: lane holds 4 consecutive edges per (nt,mt)
        #pragma unroll
        for (int nt = 0; nt < 4; ++nt) {
            const int col = (wave * 4 + nt) * 16 + m;
            const float ce = cep_l[col];
            #pragma unroll
            for (int mt = 0; mt < 4; ++mt) {
                float t0 = silu_f(acc[nt][mt][0] + ce);
                float t1 = silu_f(acc[nt][mt][1] + ce);
                float t2 = silu_f(acc[nt][mt][2] + ce);
                float t3 = silu_f(acc[nt][mt][3] + ce);
                *(uint2*)&s_tT[col][(mt * 16 + q * 4) ^ ((m & 3) << 3)] =
                    make_uint2(pk_bf16(t0, t1), pk_bf16(t2, t3));
            }
        }
    } else {
        // coord half: in-register partial dot silu(pre)*Wc2
        float p[4] = {0.f, 0.f, 0.f, 0.f};
        #pragma unroll
        for (int nt = 0; nt < 4; ++nt) {
            const int c0 = (wave * 4 + nt) * 16 + q * 4;   // 256..511
            const float4 ce = *(const float4*)&cep_l[c0];
            const float4 wv = *(const float4*)&Wc2l[c0 - 256];
            #pragma unroll
            for (int mt = 0; mt < 4; ++mt) {
                p[mt] += silu_f(acc[nt][mt][0] + ce.x) * wv.x;
                p[mt] += silu_f(acc[nt][mt][1] + ce.y) * wv.y;
                p[mt] += silu_f(acc[nt][mt][2] + ce.z) * wv.z;
                p[mt] += silu_f(acc[nt][mt][3] + ce.w) * wv.w;
            }
        }
        #pragma unroll
        for (int mt = 0; mt < 4; ++mt) {
            p[mt] += __shfl_xor(p[mt], 16);
            p[mt] += __shfl_xor(p[mt], 32);
        }
        if (lane < 16) {
            #pragma unroll
            for (int mt = 0; mt < 4; ++mt)
                s_cw[mt * 16 + lane][wave - 4] = p[mt];
        }
    }
    __syncthreads();   // s_tT / s_cw ready

    // ---- MFMA segment-sum on all 8 waves: out^T[c][r] = sum_e tT[c][e]G[e][r]
    {
        const unsigned long long mask = s_mask;
        const int nruns = __popcll(mask);
        f32x4 a2[2][4];   // [mt2 = col tile][nt = run tile]
        #pragma unroll
        for (int mt2 = 0; mt2 < 2; ++mt2)
            #pragma unroll
            for (int nt = 0; nt < 4; ++nt)
                a2[mt2][nt] = (f32x4){0.f, 0.f, 0.f, 0.f};
        #pragma unroll
        for (int ks = 0; ks < 2; ++ks) {
            bf16x8 af[2];
            #pragma unroll
            for (int mt2 = 0; mt2 < 2; ++mt2)
                af[mt2] = *(const bf16x8*)&s_tT[(wave * 2 + mt2) * 16 + m]
                                           [(ks * 32 + q * 8) ^ ((m & 3) << 3)];
            const unsigned* rp = (const unsigned*)&s_rid[ks * 32 + q * 8];
            const unsigned r01 = rp[0], r23 = rp[1], r45 = rp[2], r67 = rp[3];
            #pragma unroll
            for (int nt = 0; nt < 4; ++nt) {
                const unsigned n = (unsigned)(nt * 16 + m);
                unsigned gw[4];
                gw[0] = ((r01 & 0xFFFFu) == n ? 0x3F80u : 0u) |
                        ((r01 >> 16)      == n ? 0x3F800000u : 0u);
                gw[1] = ((r23 & 0xFFFFu) == n ? 0x3F80u : 0u) |
                        ((r23 >> 16)      == n ? 0x3F800000u : 0u);
                gw[2] = ((r45 & 0xFFFFu) == n ? 0x3F80u : 0u) |
                        ((r45 >> 16)      == n ? 0x3F800000u : 0u);
                gw[3] = ((r67 & 0xFFFFu) == n ? 0x3F80u : 0u) |
                        ((r67 >> 16)      == n ? 0x3F800000u : 0u);
                const bf16x8 bfr = *(const bf16x8*)gw;
                #pragma unroll
                for (int mt2 = 0; mt2 < 2; ++mt2)
                    a2[mt2][nt] = __builtin_amdgcn_mfma_f32_16x16x32_bf16(
                        af[mt2], bfr, a2[mt2][nt], 0, 0, 0);
            }
        }
        // Interior runs: exclusive owner of the dst row (dst-sorted edges)
        // -> plain coalesced float4 stores. Boundary runs (first/last of the
        // block) may be shared with neighbor blocks -> atomicAdd.
        #pragma unroll
        for (int nt = 0; nt < 4; ++nt) {
            const int r = nt * 16 + m;
            if (r < nruns) {
                float* bp = Tbar + (size_t)s_rdst[r] * 256;
                const bool bdry = (r == 0) || (r == nruns - 1);
                #pragma unroll
                for (int mt2 = 0; mt2 < 2; ++mt2) {
                    const int c = (wave * 2 + mt2) * 16 + q * 4;
                    if (bdry) {
                        atomicAdd(&bp[c],     a2[mt2][nt][0]);
                        atomicAdd(&bp[c + 1], a2[mt2][nt][1]);
                        atomicAdd(&bp[c + 2], a2[mt2][nt][2]);
                        atomicAdd(&bp[c + 3], a2[mt2][nt][3]);
                    } else {
                        *(f32x4*)&bp[c] = a2[mt2][nt];
                    }
                }
            }
        }
    }
    if (wave == 2) {
        // finalize coord weights, scatter x
        const int e = lane;
        float4 pv = *(const float4*)&s_cw[e][0];
        float cw = pv.x + pv.y + pv.z + pv.w;
        int sn = s_src[e], dn = s_dst[e];
        float dx0 = x_in[sn * 3 + 0] - x_in[dn * 3 + 0];
        float dx1 = x_in[sn * 3 + 1] - x_in[dn * 3 + 1];
        float dx2 = x_in[sn * 3 + 2] - x_in[dn * 3 + 2];
        atomicAdd(&x_out[dn * 3 + 0], cw * dx0);
        atomicAdd(&x_out[dn * 3 + 1], cw * dx1);
        atomicAdd(&x_out[dn * 3 + 2], cw * dx2);
    }
}

// ======================= node kernel: h += Tbar@Wn2 + deg*bn2 ===============
__global__ __launch_bounds__(256) void node_kernel(
        const float* __restrict__ Tbar, const int* __restrict__ deg,
        const unsigned short* __restrict__ wn2_l, const float* __restrict__ bn2l,
        float* __restrict__ h, unsigned short* __restrict__ hbf)
{
    const int nb = blockIdx.x * 64;
    const int tid = threadIdx.x;
    const int wave = tid >> 6, lane = tid & 63;
    const int m = lane & 15, q = lane >> 4;

    f32x4 acc[2][4];
    #pragma unroll
    for (int nt = 0; nt < 2; ++nt)
        #pragma unroll
        for (int mt = 0; mt < 4; ++mt)
            acc[nt][mt] = (f32x4){0.f, 0.f, 0.f, 0.f};

    #pragma unroll
    for (int ks = 0; ks < 8; ++ks) {
        bf16x8 af[4];
        #pragma unroll
        for (int mt = 0; mt < 4; ++mt) {
            const int node = nb + mt * 16 + m;
            if (node < NN) {
                const float* tp = Tbar + (size_t)node * 256 + ks * 32 + q * 8;
                float4 f0 = *(const float4*)tp;
                float4 f1 = *(const float4*)(tp + 4);
                unsigned u[4] = { pk_bf16(f0.x, f0.y), pk_bf16(f0.z, f0.w),
                                  pk_bf16(f1.x, f1.y), pk_bf16(f1.z, f1.w) };
                af[mt] = *(const bf16x8*)u;
            } else {
                af[mt] = (bf16x8){0,0,0,0,0,0,0,0};
            }
        }
        #pragma unroll
        for (int nt = 0; nt < 2; ++nt) {
            bf16x8 wf = *(const bf16x8*)(wn2_l +
                ((size_t)((wave * 2 + nt) * 8 + ks) * 64 + lane) * 8);
            #pragma unroll
            for (int mt = 0; mt < 4; ++mt)
                acc[nt][mt] = __builtin_amdgcn_mfma_f32_16x16x32_bf16(af[mt], wf, acc[nt][mt], 0, 0, 0);
        }
    }
    #pragma unroll
    for (int nt = 0; nt < 2; ++nt) {
        const int col = (wave * 2 + nt) * 16 + m;
        const float bb = bn2l[col];
        #pragma unroll
        for (int mt = 0; mt < 4; ++mt) {
            #pragma unroll
            for (int i = 0; i < 4; ++i) {
                const int node = nb + mt * 16 + q * 4 + i;
                if (node < NN) {
                    float val = acc[nt][mt][i] + (float)deg[node] * bb
                              + h[(size_t)node * CD + col];
                    h[(size_t)node * CD + col] = val;
                    hbf[(size_t)node * CD + col] = f2bf(val);
                }
            }
        }
    }
}

// ======================= final layernorm ====================================
__global__ __launch_bounds__(256) void final_kernel(
        const float* __restrict__ h, const float* __restrict__ x,
        const float* __restrict__ gamma, const float* __restrict__ beta,
        float* __restrict__ out)
{
    const int lane = threadIdx.x & 63;
    const int wave = threadIdx.x >> 6;
    const int n = blockIdx.x * 4 + wave;
    float v0 = h[(size_t)n * CD + lane];
    float v1 = h[(size_t)n * CD + 64 + lane];
    float ssum = v0 + v1;
    for (int off = 32; off; off >>= 1) ssum += __shfl_xor(ssum, off);
    float mu = ssum * (1.f / 128.f);
    float d0 = v0 - mu, d1 = v1 - mu;
    float sq = d0 * d0 + d1 * d1;
    for (int off = 32; off; off >>= 1) sq += __shfl_xor(sq, off);
    float rstd = rsqrtf(sq * (1.f / 128.f) + 1e-5f);
    out[(size_t)n * CD + lane]      = gamma[lane]      * d0 * rstd + beta[lane];
    out[(size_t)n * CD + 64 + lane] = gamma[64 + lane] * d1 * rstd + beta[64 + lane];
    if (threadIdx.x < 12) {
        int nn = blockIdx.x * 4 + threadIdx.x / 3;
        int c = threadIdx.x % 3;
        out[(size_t)NN * CD + nn * 3 + c] = x[nn * 3 + c];
    }
}

static inline size_t align_up(size_t v) { return (v + 255) & ~(size_t)255; }

extern "C" void kernel_launch(void* const* d_in, const int* in_sizes, int n_in,
                              void* d_out, int out_size, void* d_ws, size_t ws_size,
                              hipStream_t stream)
{
    const float* single = (const float*)d_in[0];
    const float* coords = (const float*)d_in[2];
    const int*   eidx   = (const int*)d_in[3];
    const float* edist  = (const float*)d_in[4];
    const float* We1 = (const float*)d_in[5];
    const float* be1 = (const float*)d_in[6];
    const float* We2 = (const float*)d_in[7];
    const float* be2 = (const float*)d_in[8];
    const float* Wn1 = (const float*)d_in[9];
    const float* bn1 = (const float*)d_in[10];
    const float* Wn2 = (const float*)d_in[11];
    const float* bn2 = (const float*)d_in[12];
    const float* Wc1 = (const float*)d_in[13];
    const float* bc1 = (const float*)d_in[14];
    const float* Wc2 = (const float*)d_in[15];
    const float* gamma = (const float*)d_in[16];
    const float* beta  = (const float*)d_in[17];
    float* out = (float*)d_out;

    char* w = (char*)d_ws;
    float* h0  = (float*)w;  w += align_up((size_t)NN * CD * 4);
    float* x0  = (float*)w;  w += align_up((size_t)NN * 3 * 4);
    float* x1  = (float*)w;  w += align_up((size_t)NN * 3 * 4);
    unsigned short* hbf  = (unsigned short*)w; w += align_up((size_t)NN * CD * 2);
    unsigned short* wbig = (unsigned short*)w; w += align_up((size_t)4 * 512 * 320 * 2);
    unsigned short* wn2s = (unsigned short*)w; w += align_up((size_t)4 * 256 * 128 * 2);
    float* cep = (float*)w;  w += align_up((size_t)4 * 512 * 4);
    int* hist   = (int*)w;   w += align_up((size_t)HBINS * 4);
    int* offs   = (int*)w;   w += align_up((size_t)HBINS * 4);
    int* cursor = (int*)w;   w += align_up((size_t)HBINS * 4);
    int* bsum   = (int*)w;   w += align_up((size_t)256 * 4);
    int* ssrc   = (int*)w;   w += align_up((size_t)NE * 4);
    int* sdst   = (int*)w;   w += align_up((size_t)NE * 4);
    float* sdist = (float*)w; w += align_up((size_t)NE * 4);
    float* Tbar = (float*)w; w += align_up((size_t)NN * 256 * 4);

    // ---- sort edges by dst (once; constant across layers) ----
    hipMemsetAsync(hist, 0, (size_t)HBINS * 4, stream);
    hist_kernel<<<(NE + 255) / 256, 256, 0, stream>>>(eidx + NE, hist);
    scan1_kernel<<<HBINS / 256, 256, 0, stream>>>(hist, offs, bsum);
    scan2_kernel<<<1, 256, 0, stream>>>(bsum);
    scan3_kernel<<<HBINS / 256, 256, 0, stream>>>(offs, bsum, cursor);
    scatter_kernel<<<(NE + 255) / 256, 256, 0, stream>>>(eidx, edist, cursor, ssrc, sdst, sdist);

    // ---- weight prep ----
    wbig_prep<<<dim3(320, 4), 64, 0, stream>>>(We2, Wn1, Wc1, wbig);
    wn2_prep<<<dim3(64, 4), 64, 0, stream>>>(Wn2, wn2s);
    cep_prep<<<4, 512, 0, stream>>>(be2, Wn1, Wc1, bn1, bc1, cep);

    hipMemcpyAsync(h0, single, (size_t)NN * CD * 4, hipMemcpyDeviceToDevice, stream);
    hipMemcpyAsync(x0, coords, (size_t)NN * 3 * 4, hipMemcpyDeviceToDevice, stream);
    conv_kernel<<<(NN * CD) / 1024, 256, 0, stream>>>(single, hbf);

    float* xc = x0; float* xn = x1;
    for (int l = 0; l < 4; ++l) {
        hipMemsetAsync(Tbar, 0, (size_t)NN * 256 * 4, stream);
        hipMemcpyAsync(xn, xc, (size_t)NN * 3 * 4, hipMemcpyDeviceToDevice, stream);
        edge_kernel<<<NE / EPB, 512, 0, stream>>>(
            ssrc, sdst, sdist,
            We1 + l * 64, be1 + l * 64,
            hbf,
            wbig + (size_t)l * 512 * 320,
            cep + l * 512,
            Wc2 + l * 256,
            xc, Tbar, xn);
        node_kernel<<<(NN + 63) / 64, 256, 0, stream>>>(
            Tbar, hist,
            wn2s + (size_t)l * 256 * 128,
            bn2 + l * CD, h0, hbf);
        float* t = xc; xc = xn; xn = t;
    }
    final_kernel<<<NN / 4, 256, 0, stream>>>(h0, xc, gamma, beta, out);
}